// Round 10
// baseline (1084.725 us; speedup 1.0000x reference)
//
#include <hip/hip_runtime.h>
#include <hip/hip_bf16.h>

// Elman RNN: B=256, T=512, H=1024, O=256 (fp32 in/out), MI355X gfx950.
// Round 10: revert to the proven round-7 structure (XCD-L2 experiments of
// r8/r9 caused infra-level failures; abandoned). One change vs r7:
// stage_quarter's retry path spins on a cheap 2-dword-per-lane sentinel
// probe instead of re-issuing the full 4-KB/wave bulk fetch, cutting MALL
// poll-burst queueing ~8-16x. Bulk fetch's per-dword tag check remains the
// only correctness gate.
// Structure: 128 WGs = 16 batch-groups x 8 members, 512 threads (2
// col-groups x 4 k-quarters). W_ih slice (1024x128) in registers as fp16
// A-frags (A=W^T). h double-buffered fp16 in d_ws; every dword carries a
// step-parity tag in bit 0 (LSB of low fp16; <=2^-10, finer than bf16).
// sc0|sc1 write-through stores + bypass loads at the MALL; no flags, no
// fences. Wave (cg,kq) stages only region kq (members 2kq,2kq+1), pairwise
// LDS sync, one WG barrier/step at the b128 double-buffered k-exchange.

#define Bsz 256
#define Tn  512
#define Hn  1024
#define On  256

typedef __attribute__((ext_vector_type(8))) _Float16 f16x8;  // 4 VGPR
typedef __attribute__((ext_vector_type(4))) float f32x4;
typedef __attribute__((ext_vector_type(4))) int   i32x4;
typedef __attribute__((ext_vector_type(2))) int   i32x2;

__device__ __forceinline__ unsigned f2h(float f) {
    _Float16 h = (_Float16)f;
    union { _Float16 h; unsigned short s; } u; u.h = h;
    return (unsigned)u.s;
}

__device__ __forceinline__ f16x8 as_f16x8(i32x4 v) {
    union { i32x4 i; f16x8 h; } u; u.i = v; return u.h;
}

// tanh = (e^{2x}-1)/(e^{2x}+1); |err| ~1e-6 << fp16 rounding.
__device__ __forceinline__ float fast_tanh(float x) {
    float xc = fminf(fmaxf(x, -9.f), 9.f);
    float e  = __builtin_amdgcn_exp2f(xc * 2.8853900817779268f);
    return (e - 1.f) * __builtin_amdgcn_rcpf(e + 1.f);
}

#define MFMA_F16 __builtin_amdgcn_mfma_f32_16x16x32_f16

// Poll-stage region kq (cols kq*256..+255), rows r0..r0+7, into swizzled
// LDS. Bulk: 4 loads/lane, each instr = lanes 0-31 row r / lanes 32-63 row
// r+1, 512B contiguous per row (full 128B lines). Retry path: spin on a
// 2-dword sentinel (rows r0/r0+1 via a0, rows r0+6/r0+7 via a3, cols
// spread over both source members) until fresh, then re-issue the bulk.
__device__ __forceinline__ void stage_quarter(const short* __restrict__ hsrc,
                                              short* __restrict__ htile,
                                              int row0, int cg, int kq,
                                              int lane, unsigned tag) {
    const int half = lane >> 5, gl = lane & 31, r0 = cg * 8;
    const short* a0 = hsrc + (size_t)(row0 + r0 + half) * Hn + kq * 256 + gl * 8;
    const short* a1 = a0 + 2 * Hn;
    const short* a2 = a0 + 4 * Hn;
    const short* a3 = a0 + 6 * Hn;
    i32x4 t0, t1, t2, t3;
    for (;;) {
        asm volatile(
            "global_load_dwordx4 %0, %4, off sc0 sc1\n\t"
            "global_load_dwordx4 %1, %5, off sc0 sc1\n\t"
            "global_load_dwordx4 %2, %6, off sc0 sc1\n\t"
            "global_load_dwordx4 %3, %7, off sc0 sc1\n\t"
            "s_waitcnt vmcnt(0)"
            : "=&v"(t0), "=&v"(t1), "=&v"(t2), "=&v"(t3)
            : "v"(a0), "v"(a1), "v"(a2), "v"(a3) : "memory");
        unsigned bad = 0;
#pragma unroll
        for (int e = 0; e < 4; ++e)
            bad |= (unsigned)(t0[e] ^ tag) | (unsigned)(t1[e] ^ tag) |
                   (unsigned)(t2[e] ^ tag) | (unsigned)(t3[e] ^ tag);
        if (!__any(bad & 1u)) break;
        // Cheap sentinel spin: 2 dwords/lane instead of 64B/lane.
        unsigned p0, p3;
        do {
            asm volatile(
                "global_load_dword %0, %2, off sc0 sc1\n\t"
                "global_load_dword %1, %3, off sc0 sc1\n\t"
                "s_waitcnt vmcnt(0)"
                : "=&v"(p0), "=&v"(p3)
                : "v"(a0), "v"(a3) : "memory");
        } while (__any(((p0 ^ tag) | (p3 ^ tag)) & 1u));
    }
    i32x4 tv[4] = {t0, t1, t2, t3};
#pragma unroll
    for (int p = 0; p < 4; ++p) {
        int row = r0 + 2 * p + half;
        int g   = kq * 32 + gl;
        int idx = row * 128 + (g ^ (row & 7));
        *(i32x4*)(htile + idx * 8) = tv[p];
    }
}

__global__ __launch_bounds__(512, 2) void rnn_kernel(
    const float* __restrict__ x,      // [B][T]
    const float* __restrict__ W_ih,   // [1+H][H]
    const float* __restrict__ b_ih,   // [H]
    const float* __restrict__ W_ho,   // [H][O]
    const float* __restrict__ b_ho,   // [O]
    float* __restrict__ out,          // [B][O]
    short* __restrict__ hbuf)         // ws: 2 * B * H fp16
{
    const int tid  = threadIdx.x;
    const int lane = tid & 63;
    const int w    = tid >> 6;      // wave 0..7
    const int cg   = w >> 2;        // col-group 0..1 (64 cols each)
    const int kq   = w & 3;         // k-quarter 0..3; owns m-tile kq of its cg
    const int q    = lane >> 4;
    const int n    = lane & 15;     // batch row (B/D col)

    const int i = blockIdx.x & 15;  // batch group
    const int j = blockIdx.x >> 4;  // member 0..7
    const int colbase = j * 128 + cg * 64;
    const int owncol  = colbase + kq * 16 + 4 * q;  // owner lane's 4 h cols
    const int row0    = i * 16;

    __shared__ float x_lds[16][Tn + 1];     // 32.8 KB
    __shared__ short htile[16 * Hn];        // 32 KB swizzled fp16 h slice
    __shared__ float redbuf[2][8 * 3 * 256];// 48 KB b128 partial exchange
    __shared__ int   pairflag[4];           // region-pair arrival counters

    if (tid < 4) pairflag[tid] = 0;

    // Stage x rows (coalesced fp32).
    for (int idx = tid; idx < 16 * Tn; idx += 512) {
        int r = idx >> 9, tt = idx & (Tn - 1);
        x_lds[r][tt] = x[(row0 + r) * Tn + tt];
    }

    // A = W^T frags (fp16): wave (cg,kq), tile mt: lane (q,n) holds
    // A[m=n][k=kq*256+ks*32+q*8+e] = W_ih[1+k][colbase+mt*16+n].
    f16x8 wfrag[32];
#pragma unroll
    for (int mt = 0; mt < 4; ++mt)
#pragma unroll
        for (int ks = 0; ks < 8; ++ks) {
#pragma unroll
            for (int e = 0; e < 8; ++e) {
                int k = kq * 256 + ks * 32 + q * 8 + e;
                wfrag[mt * 8 + ks][e] =
                    (_Float16)W_ih[(size_t)(1 + k) * Hn + colbase + mt * 16 + n];
            }
        }
    const float4 bias4 = *(const float4*)(b_ih + owncol);
    const float4 w04   = *(const float4*)(W_ih + owncol);  // row 0 (x weight)

    __syncthreads();

    short* h0 = hbuf;
    short* h1 = hbuf + Bsz * Hn;
    const int swn   = n & 7;
    const int gbase = kq * 32;
    const int slot  = (q * 16 + n) * 4;   // lane's 16B slot in a redbuf plane
    const f32x4 zero4 = {0.f, 0.f, 0.f, 0.f};

    for (int t = 0; t < Tn; ++t) {
        const float xv = x_lds[n][t];
        f32x4 aown = {bias4.x + xv * w04.x, bias4.y + xv * w04.y,
                      bias4.z + xv * w04.z, bias4.w + xv * w04.w};
        f32x4 hv;

        if (t > 0) {
            // Poll + stage ONLY region kq (our 2 source members).
            stage_quarter((t & 1) ? h1 : h0, htile, row0, cg, kq, lane,
                          (unsigned)((t + 1) >> 1) & 1u);
            // Pairwise sync with region partner (other cg, same kq).
            asm volatile("s_waitcnt lgkmcnt(0)" ::: "memory");
            if (lane == 0)
                __hip_atomic_fetch_add(&pairflag[kq], 1, __ATOMIC_RELAXED,
                                       __HIP_MEMORY_SCOPE_WORKGROUP);
            while (__hip_atomic_load(&pairflag[kq], __ATOMIC_RELAXED,
                                     __HIP_MEMORY_SCOPE_WORKGROUP) < 2 * t) {}
            asm volatile("" ::: "memory");

            f32x4 acc0 = (kq == 0) ? aown : zero4;
            f32x4 acc1 = (kq == 1) ? aown : zero4;
            f32x4 acc2 = (kq == 2) ? aown : zero4;
            f32x4 acc3 = (kq == 3) ? aown : zero4;
            const i32x4* lrow = (const i32x4*)(htile + n * Hn);
#pragma unroll
            for (int ks = 0; ks < 8; ++ks) {
                f16x8 b = as_f16x8(lrow[(gbase + ks * 4 + q) ^ swn]);
                acc0 = MFMA_F16(wfrag[0 * 8 + ks], b, acc0, 0, 0, 0);
                acc1 = MFMA_F16(wfrag[1 * 8 + ks], b, acc1, 0, 0, 0);
                acc2 = MFMA_F16(wfrag[2 * 8 + ks], b, acc2, 0, 0, 0);
                acc3 = MFMA_F16(wfrag[3 * 8 + ks], b, acc3, 0, 0, 0);
            }

            // Exchange k-partials, b128 conflict-free, double-buffered.
            float* rb = redbuf[t & 1];
#define WRITE_PART(MT, ACC)                                                  \
            if (kq != MT) {                                                  \
                int src = (kq < MT) ? kq : kq - 1;                           \
                *(f32x4*)(rb + ((cg * 4 + MT) * 3 + src) * 256 + slot) = ACC;\
            }
            WRITE_PART(0, acc0)
            WRITE_PART(1, acc1)
            WRITE_PART(2, acc2)
            WRITE_PART(3, acc3)
#undef WRITE_PART
            __syncthreads();

            hv = (kq == 0) ? acc0 : (kq == 1) ? acc1 : (kq == 2) ? acc2 : acc3;
            const float* bp = rb + (cg * 4 + kq) * 3 * 256 + slot;
            f32x4 p0 = *(const f32x4*)(bp);
            f32x4 p1 = *(const f32x4*)(bp + 256);
            f32x4 p2 = *(const f32x4*)(bp + 512);
            hv = hv + p0 + p1 + p2;
        } else {
            hv = aown;
        }

        // Store h_{t+1}: buffer (t+1)&1, tag ((t+2)>>1)&1 in bit 0 of every
        // dword. Fire-and-forget write-through.
        unsigned tagn = (unsigned)((t + 2) >> 1) & 1u;
        unsigned e0 = f2h(fast_tanh(hv[0])), e1 = f2h(fast_tanh(hv[1]));
        unsigned e2 = f2h(fast_tanh(hv[2])), e3 = f2h(fast_tanh(hv[3]));
        i32x2 pk;
        pk[0] = (int)(((e0 & ~1u) | tagn) | (e1 << 16));
        pk[1] = (int)(((e2 & ~1u) | tagn) | (e3 << 16));
        short* hdst = (((t + 1) & 1) ? h1 : h0) + (size_t)(row0 + n) * Hn + owncol;
        asm volatile("global_store_dwordx2 %0, %1, off sc0 sc1"
                     :: "v"(hdst), "v"(pk) : "memory");
    }

    // ---- Epilogue: out[16i..+16][32j..+32] = h_T @ W_ho + b_ho ----
    // h_512 in buffer 0, tag 0.
    stage_quarter(h0, htile, row0, cg, kq, lane, 0u);
    __syncthreads();

    f32x4 e0 = zero4, e1 = zero4;        // nt = 0,1 (16 out-cols each)
    {
        const i32x4* lrow = (const i32x4*)(htile + n * Hn);
#pragma unroll
        for (int kk = 0; kk < 4; ++kk) {
            f16x8 af = as_f16x8(lrow[(w * 16 + kk * 4 + q) ^ swn]);
            f16x8 b0, b1;
#pragma unroll
            for (int e = 0; e < 8; ++e) {
                const float* wp = W_ho +
                    (size_t)(w * 128 + kk * 32 + q * 8 + e) * On + j * 32 + n;
                b0[e] = (_Float16)wp[0];
                b1[e] = (_Float16)wp[16];
            }
            e0 = MFMA_F16(af, b0, e0, 0, 0, 0);
            e1 = MFMA_F16(af, b1, e1, 0, 0, 0);
        }
    }
    {   // scratch in redbuf[0]: [w][16 rows][33]: D[m=4q+r][col=nt*16+n].
        float* re = redbuf[0] + w * 528;
#pragma unroll
        for (int r = 0; r < 4; ++r) {
            re[(4 * q + r) * 33 + n]      = e0[r];
            re[(4 * q + r) * 33 + 16 + n] = e1[r];
        }
    }
    __syncthreads();
    {
        int r = tid >> 5, c = tid & 31;
        float s = b_ho[j * 32 + c];
#pragma unroll
        for (int w8 = 0; w8 < 8; ++w8)
            s += redbuf[0][w8 * 528 + r * 33 + c];
        out[(size_t)(row0 + r) * On + j * 32 + c] = s;
    }
}

extern "C" void kernel_launch(void* const* d_in, const int* in_sizes, int n_in,
                              void* d_out, int out_size, void* d_ws, size_t ws_size,
                              hipStream_t stream) {
    const float* x    = (const float*)d_in[0];
    const float* W_ih = (const float*)d_in[1];
    const float* b_ih = (const float*)d_in[2];
    const float* W_ho = (const float*)d_in[3];
    const float* b_ho = (const float*)d_in[4];
    float* out = (float*)d_out;

    size_t need = (size_t)2 * Bsz * Hn * sizeof(short);
    if (ws_size < need) return;

    short* hbuf = (short*)d_ws;

    rnn_kernel<<<128, 512, 0, stream>>>(x, W_ih, b_ih, W_ho, b_ho, out, hbuf);
}